// Round 13
// baseline (923.968 us; speedup 1.0000x reference)
//
#include <hip/hip_runtime.h>

#define NN    50000
#define NE    800000
#define INF_  256
#define HIDF  128
#define OUTF  64
#define NBUCK 196        // ceil(50000/256) coarse buckets, 256 nodes each
#define CAP   5120       // per-bucket region capacity
#define CHUNK 2048       // edges per part1 block-task
#define NPART1 ((NE + CHUNK - 1) / CHUNK)   // 391
#define NLIN1  ((NN + 63) / 64)             // 782
#define NPREP  160                          // 40960 / 256
#define GRID  1536                          // 6 blocks/CU, co-resident by __launch_bounds__(256,6)
#define NWAVE (GRID * 4)                    // 6144 waves

typedef unsigned int uint;
typedef unsigned short ushort;
typedef __attribute__((ext_vector_type(8))) short short8;
typedef __attribute__((ext_vector_type(4))) float float4v;

__device__ __forceinline__ short f2bf(float f) {
    union { float f; unsigned u; } v; v.f = f;
    unsigned r = v.u + 0x7fffu + ((v.u >> 16) & 1u);   // RNE
    return (short)(r >> 16);
}
__device__ __forceinline__ float bflo(uint u) {
    union { uint u; float f; } v; v.u = u << 16; return v.f;
}
__device__ __forceinline__ float bfhi(uint u) {
    union { uint u; float f; } v; v.u = u & 0xffff0000u; return v.f;
}

struct P1Mem {
    int hist[NBUCK], lofs[NBUCK], cur[NBUCK], gstart[NBUCK];
    int ws[4];
    int ltgt[CHUNK], lsrc[CHUNK];
};
struct P2Mem { int hist[256], cur[256], ws[4]; };
union SMem { P1Mem p1; P2Mem p2; };   // 19.6 KB

// software grid barrier: release-fence + device atomic arrive + agent-scope spin + acquire-fence.
// Correct because all GRID blocks are co-resident (6/CU forced by launch bounds).
__device__ __forceinline__ void gbar(int* bar, int target) {
    __syncthreads();
    if (threadIdx.x == 0) {
        __threadfence();                       // release: write back this XCD's dirty lines
        atomicAdd(bar, 1);                     // device-scope arrive
        while (__hip_atomic_load(bar, __ATOMIC_RELAXED, __HIP_MEMORY_SCOPE_AGENT) < target)
            __builtin_amdgcn_s_sleep(8);
        __threadfence();                       // acquire: invalidate stale lines
    }
    __syncthreads();
}

// 256-thread block exclusive scan (ws = 4-int shared scratch). All 256 call.
__device__ __forceinline__ int excl_scan256(int v, int* ws) {
    int lane = threadIdx.x & 63, wv = threadIdx.x >> 6;
    int x = v;
    #pragma unroll
    for (int o = 1; o < 64; o <<= 1) {
        int y = __shfl_up(x, o);
        if (lane >= o) x += y;
    }
    if (lane == 63) ws[wv] = x;
    __syncthreads();
    int add = 0;
    #pragma unroll
    for (int w = 0; w < 4; w++) add += (w < wv) ? ws[w] : 0;
    return x + add - v;
}

// ---------------- prep: weight transpose + zero bcur + zero barrier ----------------
__global__ __launch_bounds__(256) void k_prep(const float* __restrict__ W1, const float* __restrict__ W2,
                                              short* __restrict__ W1f, short* __restrict__ W2f,
                                              int* __restrict__ bcur, int* __restrict__ bar) {
    if (blockIdx.x == NPREP) {
        if (threadIdx.x < NBUCK) bcur[threadIdx.x] = 0;
        if (threadIdx.x == 255) *bar = 0;
        return;
    }
    int i = blockIdx.x * 256 + threadIdx.x;
    if (i < INF_ * HIDF) {
        int kk = i & 7, t = i >> 3;
        int m_l = t & 15, q = (t >> 4) & 3, s = t >> 6;
        int nb = s & 7, kc = s >> 3;
        int k = kc * 32 + q * 8 + kk, n = nb * 16 + m_l;
        W1f[i] = f2bf(W1[k * HIDF + n]);
    } else {
        int i2 = i - INF_ * HIDF;
        int kk = i2 & 7, t = i2 >> 3;
        int m_l = t & 15, q = (t >> 4) & 3, s = t >> 6;
        int nb = s & 3, kc = s >> 2;
        int k = kc * 32 + q * 8 + kk, n = nb * 16 + m_l;
        W2f[i2] = f2bf(W2[k * OUTF + n]);
    }
}

__global__ __launch_bounds__(256, 6) void k_mega(
    const float* __restrict__ X, const int* __restrict__ src, const int* __restrict__ tgt,
    const float* __restrict__ b1,
    const float* __restrict__ a1w, const float* __restrict__ a1b,
    const float* __restrict__ b2,
    const float* __restrict__ a2w, const float* __restrict__ a2b,
    ushort* __restrict__ Hb, ushort* __restrict__ Hagg,
    const short* __restrict__ W1f, const short* __restrict__ W2f,
    float* __restrict__ s1s, float* __restrict__ s1t,
    float* __restrict__ s2s, float* __restrict__ s2t,
    int* __restrict__ bcur, uint2* __restrict__ pairs, int* __restrict__ fsrc,
    int* __restrict__ nbeg, int* __restrict__ ncnt, int* __restrict__ bar,
    float* __restrict__ out)
{
    __shared__ SMem sm;
    int bx = blockIdx.x;
    int tid = threadIdx.x;

    // ================= P1: part1 (coarse sort) || linear1 + s1 =================
    if (bx < NPART1) {
        for (int i = tid; i < NBUCK; i += 256) sm.p1.hist[i] = 0;
        __syncthreads();

        int base = bx * CHUNK;
        int cnt = NE - base; if (cnt > CHUNK) cnt = CHUNK;

        int t_[8], s_[8];
        #pragma unroll
        for (int k = 0; k < 8; k++) {
            int idx = k * 256 + tid;
            if (idx < cnt) {
                int j = base + idx;
                t_[k] = tgt[j]; s_[k] = src[j];
                atomicAdd(&sm.p1.hist[t_[k] >> 8], 1);
            } else t_[k] = -1;
        }
        __syncthreads();

        int v = (tid < NBUCK) ? sm.p1.hist[tid] : 0;
        int excl = excl_scan256(v, sm.p1.ws);
        if (tid < NBUCK) {
            sm.p1.lofs[tid] = excl;
            sm.p1.cur[tid] = excl;
            sm.p1.gstart[tid] = atomicAdd(&bcur[tid], v);
        }
        __syncthreads();

        #pragma unroll
        for (int k = 0; k < 8; k++) {
            if (t_[k] >= 0) {
                int b = t_[k] >> 8;
                int pos = atomicAdd(&sm.p1.cur[b], 1);
                sm.p1.ltgt[pos] = t_[k]; sm.p1.lsrc[pos] = s_[k];
            }
        }
        __syncthreads();

        for (int j = tid; j < cnt; j += 256) {
            int tv = sm.p1.ltgt[j];
            int b = tv >> 8;
            int dst = sm.p1.gstart[b] + (j - sm.p1.lofs[b]);
            pairs[(size_t)b * CAP + dst] = make_uint2((uint)tv, (uint)sm.p1.lsrc[j]);
        }
    } else if (bx < NPART1 + NLIN1) {
        int bid = bx - NPART1;
        int w = tid >> 6;
        int l = tid & 63;
        int m_l = l & 15, q = l >> 4;
        int row0 = bid * 64 + w * 16;
        int rA0 = row0 + m_l;
        int rc0 = rA0 < NN ? rA0 : NN - 1;
        const float* pa0 = X + (size_t)rc0 * INF_ + q * 8;
        const short8* Bp = (const short8*)W1f;

        float4v acc[8] = {};
        #pragma unroll
        for (int kc = 0; kc < 8; kc++) {
            float4 u0 = *(const float4*)(pa0 + kc * 32);
            float4 u1 = *(const float4*)(pa0 + kc * 32 + 4);
            short8 a0;
            a0[0] = f2bf(u0.x); a0[1] = f2bf(u0.y); a0[2] = f2bf(u0.z); a0[3] = f2bf(u0.w);
            a0[4] = f2bf(u1.x); a0[5] = f2bf(u1.y); a0[6] = f2bf(u1.z); a0[7] = f2bf(u1.w);
            #pragma unroll
            for (int n = 0; n < 8; n++) {
                short8 b = Bp[(kc * 8 + n) * 64 + l];
                acc[n] = __builtin_amdgcn_mfma_f32_16x16x32_bf16(a0, b, acc[n], 0, 0, 0);
            }
        }

        float vs_r[4] = {0.f, 0.f, 0.f, 0.f}, vt_r[4] = {0.f, 0.f, 0.f, 0.f};
        #pragma unroll
        for (int n = 0; n < 8; n++) {
            int col = n * 16 + m_l;
            float bias = b1[col];
            float aw0 = a1w[col], aw1 = a1w[HIDF + col];
            #pragma unroll
            for (int r = 0; r < 4; r++) {
                int row = row0 + q * 4 + r;
                float v = acc[n][r] + bias;
                v = v > 0.f ? v : expm1f(v);   // elu
                vs_r[r] += v * aw0; vt_r[r] += v * aw1;
                if (row < NN) Hb[(size_t)row * HIDF + col] = (ushort)f2bf(v);
            }
        }
        #pragma unroll
        for (int r = 0; r < 4; r++) {
            #pragma unroll
            for (int o = 1; o < 16; o <<= 1) {
                vs_r[r] += __shfl_xor(vs_r[r], o);
                vt_r[r] += __shfl_xor(vt_r[r], o);
            }
        }
        if (m_l == 0) {
            #pragma unroll
            for (int r = 0; r < 4; r++) {
                int row = row0 + q * 4 + r;
                if (row < NN) { s1s[row] = vs_r[r]; s1t[row] = vt_r[r]; }
            }
        }
    }
    gbar(bar, GRID);

    // ================= P2: part2 (fine sort per bucket) =================
    if (bx < NBUCK) {
        int b = bx;
        int cnt = __builtin_amdgcn_readfirstlane(bcur[b]);
        sm.p2.hist[tid] = 0;
        __syncthreads();

        const uint2* pb = pairs + (size_t)b * CAP;
        for (int j = tid; j < cnt; j += 256) {
            uint2 e = pb[j];
            atomicAdd(&sm.p2.hist[e.x & 255], 1);
        }
        __syncthreads();

        int v = sm.p2.hist[tid];
        int excl = excl_scan256(v, sm.p2.ws);
        int node = (b << 8) + tid;
        if (node < NN) { nbeg[node] = b * CAP + excl; ncnt[node] = v; }
        sm.p2.cur[tid] = excl;
        __syncthreads();

        for (int j = tid; j < cnt; j += 256) {
            uint2 e = pb[j];
            int pos = atomicAdd(&sm.p2.cur[e.x & 255], 1);
            fsrc[(size_t)b * CAP + pos] = (int)e.y;
        }
    }
    gbar(bar, 2 * GRID);

    // ================= P3: agg1 (softmax + gather), wave-strided =================
    {
        const uint* Hb4 = (const uint*)Hb;
        uint* Hagg4 = (uint*)Hagg;
        int gw = bx * 4 + (tid >> 6);
        int lane = tid & 63;
        float gbias = a1b[0];
        for (int wid = gw; wid < NN; wid += NWAVE) {
            int beg = __builtin_amdgcn_readfirstlane(nbeg[wid]);
            int deg = __builtin_amdgcn_readfirstlane(ncnt[wid]);
            int end = beg + deg;
            float bias = gbias + s1t[wid];
            float ax = 0.f, ay = 0.f, bxx = 0.f, byy = 0.f;

            if (deg > 0 && deg <= 64) {
                int my_s = 0; float a = -INFINITY;
                if (lane < deg) {
                    my_s = fsrc[beg + lane];
                    float t = s1s[my_s] + bias;
                    a = t >= 0.f ? t : 0.2f * t;
                }
                float m = a;
                #pragma unroll
                for (int o = 32; o > 0; o >>= 1) m = fmaxf(m, __shfl_xor(m, o));
                float e = (lane < deg) ? __expf(a - m) : 0.f;
                float sum = e;
                #pragma unroll
                for (int o = 32; o > 0; o >>= 1) sum += __shfl_xor(sum, o);
                float p = e * (1.f / (sum + 1e-16f));
                for (int j = 0; j < deg; j += 8) {
                    int sA[8]; float wA[8]; uint xA[8];
                    #pragma unroll
                    for (int u = 0; u < 8; u++) { sA[u] = __shfl(my_s, j + u); wA[u] = __shfl(p, j + u); }
                    #pragma unroll
                    for (int u = 0; u < 8; u++) xA[u] = Hb4[(size_t)sA[u] * 64 + lane];
                    #pragma unroll
                    for (int u = 0; u < 8; u += 2) {
                        ax  += wA[u] * bflo(xA[u]);         ay  += wA[u] * bfhi(xA[u]);
                        bxx += wA[u + 1] * bflo(xA[u + 1]); byy += wA[u + 1] * bfhi(xA[u + 1]);
                    }
                }
            } else if (deg > 64) {
                float m = -INFINITY;
                for (int i = beg + lane; i < end; i += 64) {
                    float t = s1s[fsrc[i]] + bias;
                    t = t >= 0.f ? t : 0.2f * t;
                    m = fmaxf(m, t);
                }
                #pragma unroll
                for (int o = 32; o > 0; o >>= 1) m = fmaxf(m, __shfl_xor(m, o));
                float sum = 0.f;
                for (int i = beg + lane; i < end; i += 64) {
                    float t = s1s[fsrc[i]] + bias;
                    t = t >= 0.f ? t : 0.2f * t;
                    sum += __expf(t - m);
                }
                #pragma unroll
                for (int o = 32; o > 0; o >>= 1) sum += __shfl_xor(sum, o);
                float inv = 1.f / (sum + 1e-16f);
                for (int c = beg; c < end; c += 64) {
                    int cnt = min(64, end - c);
                    int my_s = 0; float p = 0.f;
                    if (lane < cnt) {
                        my_s = fsrc[c + lane];
                        float t = s1s[my_s] + bias;
                        t = t >= 0.f ? t : 0.2f * t;
                        p = __expf(t - m) * inv;
                    }
                    for (int j = 0; j < cnt; j += 4) {
                        int s0 = __shfl(my_s, j),     s1_ = __shfl(my_s, j + 1);
                        int s2 = __shfl(my_s, j + 2), s3 = __shfl(my_s, j + 3);
                        float w0 = __shfl(p, j),     w1 = __shfl(p, j + 1);
                        float w2 = __shfl(p, j + 2), w3 = __shfl(p, j + 3);
                        uint x0 = Hb4[(size_t)s0 * 64 + lane];
                        uint x1 = Hb4[(size_t)s1_ * 64 + lane];
                        uint x2 = Hb4[(size_t)s2 * 64 + lane];
                        uint x3 = Hb4[(size_t)s3 * 64 + lane];
                        ax  += w0 * bflo(x0); ay  += w0 * bfhi(x0);
                        bxx += w1 * bflo(x1); byy += w1 * bfhi(x1);
                        ax  += w2 * bflo(x2); ay  += w2 * bfhi(x2);
                        bxx += w3 * bflo(x3); byy += w3 * bfhi(x3);
                    }
                }
            }
            float fx = ax + bxx, fy = ay + byy;
            uint outv = (uint)(ushort)f2bf(fx) | ((uint)(ushort)f2bf(fy) << 16);
            Hagg4[(size_t)wid * 64 + lane] = outv;
        }
    }
    gbar(bar, 3 * GRID);

    // ================= P4: linear2 + s2 =================
    if (bx < NLIN1) {
        const short* Hin = (const short*)Hagg;
        int w = tid >> 6;
        int l = tid & 63;
        int m_l = l & 15, q = l >> 4;
        int row0 = bx * 64 + w * 16;
        int rA0 = row0 + m_l;
        int rc0 = rA0 < NN ? rA0 : NN - 1;
        const short* pa0 = Hin + (size_t)rc0 * HIDF + q * 8;
        const short8* Bp = (const short8*)W2f;

        float4v acc[4] = {};
        #pragma unroll
        for (int kc = 0; kc < 4; kc++) {
            short8 a0 = *(const short8*)(pa0 + kc * 32);
            #pragma unroll
            for (int n = 0; n < 4; n++) {
                short8 b = Bp[(kc * 4 + n) * 64 + l];
                acc[n] = __builtin_amdgcn_mfma_f32_16x16x32_bf16(a0, b, acc[n], 0, 0, 0);
            }
        }

        float vs_r[4] = {0.f, 0.f, 0.f, 0.f}, vt_r[4] = {0.f, 0.f, 0.f, 0.f};
        ushort* Ob = Hb;   // reuse Hb buffer for O (bf16 rows of 64)
        #pragma unroll
        for (int n = 0; n < 4; n++) {
            int col = n * 16 + m_l;
            float bias = b2[col];
            float aw0 = a2w[col], aw1 = a2w[OUTF + col];
            #pragma unroll
            for (int r = 0; r < 4; r++) {
                int row = row0 + q * 4 + r;
                float v = acc[n][r] + bias;
                vs_r[r] += v * aw0; vt_r[r] += v * aw1;
                if (row < NN) Ob[(size_t)row * OUTF + col] = (ushort)f2bf(v);
            }
        }
        #pragma unroll
        for (int r = 0; r < 4; r++) {
            #pragma unroll
            for (int o = 1; o < 16; o <<= 1) {
                vs_r[r] += __shfl_xor(vs_r[r], o);
                vt_r[r] += __shfl_xor(vt_r[r], o);
            }
        }
        if (m_l == 0) {
            #pragma unroll
            for (int r = 0; r < 4; r++) {
                int row = row0 + q * 4 + r;
                if (row < NN) { s2s[row] = vs_r[r]; s2t[row] = vt_r[r]; }
            }
        }
    }
    gbar(bar, 4 * GRID);

    // ================= P5: agg2 + log_softmax, wave-strided =================
    {
        const uint* Ob4 = (const uint*)Hb;   // O stored in Hb buffer
        int gw = bx * 4 + (tid >> 6);
        int lane = tid & 63;
        int half = lane >> 5, li = lane & 31;
        float gbias = a2b[0];
        for (int wid = gw; wid < NN; wid += NWAVE) {
            int beg = __builtin_amdgcn_readfirstlane(nbeg[wid]);
            int deg = __builtin_amdgcn_readfirstlane(ncnt[wid]);
            int end = beg + deg;
            float bias = gbias + s2t[wid];
            float a0 = 0.f, a1 = 0.f;

            if (deg > 0 && deg <= 64) {
                int my_s = 0; float a = -INFINITY;
                if (lane < deg) {
                    my_s = fsrc[beg + lane];
                    float t = s2s[my_s] + bias;
                    a = t >= 0.f ? t : 0.2f * t;
                }
                float m = a;
                #pragma unroll
                for (int o = 32; o > 0; o >>= 1) m = fmaxf(m, __shfl_xor(m, o));
                float e = (lane < deg) ? __expf(a - m) : 0.f;
                float sum = e;
                #pragma unroll
                for (int o = 32; o > 0; o >>= 1) sum += __shfl_xor(sum, o);
                float p = e * (1.f / (sum + 1e-16f));
                for (int j = 0; j < deg; j += 8) {
                    int e0 = j + half, e1 = j + 2 + half, e2 = j + 4 + half, e3 = j + 6 + half;
                    int s0 = __shfl(my_s, e0), s1_ = __shfl(my_s, e1);
                    int s2 = __shfl(my_s, e2), s3 = __shfl(my_s, e3);
                    float w0 = __shfl(p, e0), w1 = __shfl(p, e1);
                    float w2 = __shfl(p, e2), w3 = __shfl(p, e3);
                    uint x0 = Ob4[(size_t)s0 * 32 + li];
                    uint x1 = Ob4[(size_t)s1_ * 32 + li];
                    uint x2 = Ob4[(size_t)s2 * 32 + li];
                    uint x3 = Ob4[(size_t)s3 * 32 + li];
                    a0 += w0 * bflo(x0); a1 += w0 * bfhi(x0);
                    a0 += w1 * bflo(x1); a1 += w1 * bfhi(x1);
                    a0 += w2 * bflo(x2); a1 += w2 * bfhi(x2);
                    a0 += w3 * bflo(x3); a1 += w3 * bfhi(x3);
                }
            } else if (deg > 64) {
                float m = -INFINITY;
                for (int i = beg + lane; i < end; i += 64) {
                    float t = s2s[fsrc[i]] + bias;
                    t = t >= 0.f ? t : 0.2f * t;
                    m = fmaxf(m, t);
                }
                #pragma unroll
                for (int o = 32; o > 0; o >>= 1) m = fmaxf(m, __shfl_xor(m, o));
                float sum = 0.f;
                for (int i = beg + lane; i < end; i += 64) {
                    float t = s2s[fsrc[i]] + bias;
                    t = t >= 0.f ? t : 0.2f * t;
                    sum += __expf(t - m);
                }
                #pragma unroll
                for (int o = 32; o > 0; o >>= 1) sum += __shfl_xor(sum, o);
                float inv = 1.f / (sum + 1e-16f);
                for (int c = beg; c < end; c += 64) {
                    int cnt = min(64, end - c);
                    int my_s = 0; float p = 0.f;
                    if (lane < cnt) {
                        my_s = fsrc[c + lane];
                        float t = s2s[my_s] + bias;
                        t = t >= 0.f ? t : 0.2f * t;
                        p = __expf(t - m) * inv;
                    }
                    for (int j = 0; j < cnt; j += 4) {
                        int e0 = j + half, e1 = j + 2 + half;
                        int s0 = __shfl(my_s, e0), s1_ = __shfl(my_s, e1);
                        float w0 = __shfl(p, e0), w1 = __shfl(p, e1);
                        uint x0 = Ob4[(size_t)s0 * 32 + li];
                        uint x1 = Ob4[(size_t)s1_ * 32 + li];
                        a0 += w0 * bflo(x0); a1 += w0 * bfhi(x0);
                        a0 += w1 * bflo(x1); a1 += w1 * bfhi(x1);
                    }
                }
            }
            a0 += __shfl_xor(a0, 32);
            a1 += __shfl_xor(a1, 32);
            float mx = fmaxf(a0, a1);
            #pragma unroll
            for (int o = 16; o > 0; o >>= 1) mx = fmaxf(mx, __shfl_xor(mx, o));
            float es = __expf(a0 - mx) + __expf(a1 - mx);
            #pragma unroll
            for (int o = 16; o > 0; o >>= 1) es += __shfl_xor(es, o);
            float lg = __logf(es);
            if (half == 0) {
                float2 r; r.x = a0 - mx - lg; r.y = a1 - mx - lg;
                ((float2*)out)[(size_t)wid * 32 + li] = r;
            }
        }
    }
}

// ---------------- launcher ----------------

extern "C" void kernel_launch(void* const* d_in, const int* in_sizes, int n_in,
                              void* d_out, int out_size, void* d_ws, size_t ws_size,
                              hipStream_t stream) {
    const float* X   = (const float*)d_in[0];
    const int*   ei  = (const int*)d_in[1];
    const float* W1  = (const float*)d_in[2];
    const float* b1  = (const float*)d_in[3];
    const float* a1w = (const float*)d_in[4];
    const float* a1b = (const float*)d_in[5];
    const float* W2  = (const float*)d_in[6];
    const float* b2  = (const float*)d_in[7];
    const float* a2w = (const float*)d_in[8];
    const float* a2b = (const float*)d_in[9];
    const int* src = ei;           // edge_index[0]
    const int* tgt = ei + NE;      // edge_index[1]

    char* p = (char*)d_ws;
    size_t off = 0;
    auto alloc = [&](size_t bytes) -> char* {
        char* r = p + off;
        off = (off + bytes + 255) & ~(size_t)255;
        return r;
    };
    ushort* Hb    = (ushort*)alloc((size_t)NN * HIDF * 2);   // also reused for O rows
    ushort* Hagg  = (ushort*)alloc((size_t)NN * HIDF * 2);
    short* W1f    = (short*)alloc((size_t)INF_ * HIDF * 2);
    short* W2f    = (short*)alloc((size_t)HIDF * OUTF * 2);
    float* s1s    = (float*)alloc((size_t)NN * 4);
    float* s1t    = (float*)alloc((size_t)NN * 4);
    float* s2s    = (float*)alloc((size_t)NN * 4);
    float* s2t    = (float*)alloc((size_t)NN * 4);
    int*   bcur   = (int*)alloc((size_t)NBUCK * 4);
    uint2* pairs  = (uint2*)alloc((size_t)NBUCK * CAP * 8);
    int*   fsrc   = (int*)alloc((size_t)NBUCK * CAP * 4);
    int*   nbeg   = (int*)alloc((size_t)NN * 4);
    int*   ncnt   = (int*)alloc((size_t)NN * 4);
    int*   bar    = (int*)alloc(256);

    k_prep<<<NPREP + 1, 256, 0, stream>>>(W1, W2, W1f, W2f, bcur, bar);
    k_mega<<<GRID, 256, 0, stream>>>(X, src, tgt, b1, a1w, a1b, b2, a2w, a2b,
                                     Hb, Hagg, W1f, W2f, s1s, s1t, s2s, s2t,
                                     bcur, pairs, fsrc, nbeg, ncnt, bar, (float*)d_out);
}

// Round 14
// 211.562 us; speedup vs baseline: 4.3674x; 4.3674x over previous
//
#include <hip/hip_runtime.h>

#define NN    50000
#define NE    800000
#define INF_  256
#define HIDF  128
#define OUTF  64
#define NBUCK 196        // ceil(50000/256) coarse buckets, 256 nodes each
#define CAP   5120       // per-bucket region capacity
#define CHUNK 2048       // edges per part1 block
#define NPART1 ((NE + CHUNK - 1) / CHUNK)   // 391
#define NLIN1  ((NN + 63) / 64)             // 782
#define NPREP  160                          // 40960 / 256

typedef unsigned int uint;
typedef unsigned short ushort;
typedef __attribute__((ext_vector_type(8))) short short8;
typedef __attribute__((ext_vector_type(4))) float float4v;

__device__ __forceinline__ short f2bf(float f) {
    union { float f; unsigned u; } v; v.f = f;
    unsigned r = v.u + 0x7fffu + ((v.u >> 16) & 1u);   // round-to-nearest-even
    return (short)(r >> 16);
}
__device__ __forceinline__ float bflo(uint u) {
    union { uint u; float f; } v; v.u = u << 16; return v.f;
}
__device__ __forceinline__ float bfhi(uint u) {
    union { uint u; float f; } v; v.u = u & 0xffff0000u; return v.f;
}

// 256-thread block exclusive scan (ws = 4-int shared scratch). All 256 call.
__device__ __forceinline__ int excl_scan256(int v, int* ws) {
    int lane = threadIdx.x & 63, wv = threadIdx.x >> 6;
    int x = v;
    #pragma unroll
    for (int o = 1; o < 64; o <<= 1) {
        int y = __shfl_up(x, o);
        if (lane >= o) x += y;
    }
    if (lane == 63) ws[wv] = x;
    __syncthreads();
    int add = 0;
    #pragma unroll
    for (int w = 0; w < 4; w++) add += (w < wv) ? ws[w] : 0;
    return x + add - v;
}

// ---------------- prep: weight transpose to MFMA B-fragment order + zero bcur ----------------
__global__ __launch_bounds__(256) void k_prep(const float* __restrict__ W1, const float* __restrict__ W2,
                                              short* __restrict__ W1f, short* __restrict__ W2f,
                                              int* __restrict__ bcur) {
    if (blockIdx.x == NPREP) {
        if (threadIdx.x < NBUCK) bcur[threadIdx.x] = 0;
        return;
    }
    int i = blockIdx.x * 256 + threadIdx.x;
    if (i < INF_ * HIDF) {
        int kk = i & 7, t = i >> 3;
        int m_l = t & 15, q = (t >> 4) & 3, s = t >> 6;
        int nb = s & 7, kc = s >> 3;
        int k = kc * 32 + q * 8 + kk, n = nb * 16 + m_l;
        W1f[i] = f2bf(W1[k * HIDF + n]);
    } else if (i < INF_ * HIDF + HIDF * OUTF) {
        int i2 = i - INF_ * HIDF;
        int kk = i2 & 7, t = i2 >> 3;
        int m_l = t & 15, q = (t >> 4) & 3, s = t >> 6;
        int nb = s & 3, kc = s >> 2;
        int k = kc * 32 + q * 8 + kk, n = nb * 16 + m_l;
        W2f[i2] = f2bf(W2[k * OUTF + n]);
    }
}

// ---------------- fused: part1 (coarse bucket sort) + linear1 (+s1 epilogue) ----------------

__global__ __launch_bounds__(256, 3) void k_f1(const int* __restrict__ src, const int* __restrict__ tgt,
                                               int* __restrict__ bcur, uint2* __restrict__ pairs,
                                               const float* __restrict__ X, const short* __restrict__ W1f,
                                               const float* __restrict__ b1, ushort* __restrict__ Hb,
                                               const float* __restrict__ a1w, float* __restrict__ s1s,
                                               float* __restrict__ s1t) {
    if (blockIdx.x < NPART1) {
        // ================= part1 =================
        __shared__ int hist[NBUCK], lofs[NBUCK], cur[NBUCK], gstart[NBUCK];
        __shared__ int ws[4];
        __shared__ int ltgt[CHUNK], lsrc[CHUNK];
        int tid = threadIdx.x;
        for (int i = tid; i < NBUCK; i += 256) hist[i] = 0;
        __syncthreads();

        int base = blockIdx.x * CHUNK;
        int cnt = NE - base; if (cnt > CHUNK) cnt = CHUNK;

        int t_[8], s_[8];
        #pragma unroll
        for (int k = 0; k < 8; k++) {
            int idx = k * 256 + tid;
            if (idx < cnt) {
                int j = base + idx;
                t_[k] = tgt[j]; s_[k] = src[j];
                atomicAdd(&hist[t_[k] >> 8], 1);
            } else t_[k] = -1;
        }
        __syncthreads();

        int v = (tid < NBUCK) ? hist[tid] : 0;
        int excl = excl_scan256(v, ws);
        if (tid < NBUCK) {
            lofs[tid] = excl;
            cur[tid] = excl;
            gstart[tid] = atomicAdd(&bcur[tid], v);
        }
        __syncthreads();

        #pragma unroll
        for (int k = 0; k < 8; k++) {
            if (t_[k] >= 0) {
                int b = t_[k] >> 8;
                int pos = atomicAdd(&cur[b], 1);
                ltgt[pos] = t_[k]; lsrc[pos] = s_[k];
            }
        }
        __syncthreads();

        for (int j = tid; j < cnt; j += 256) {
            int tv = ltgt[j];
            int b = tv >> 8;
            int dst = gstart[b] + (j - lofs[b]);
            pairs[(size_t)b * CAP + dst] = make_uint2((uint)tv, (uint)lsrc[j]);
        }
        return;
    }
    // ================= linear1 + s1 =================
    int bid = blockIdx.x - NPART1;
    int w = threadIdx.x >> 6;
    int l = threadIdx.x & 63;
    int m_l = l & 15, q = l >> 4;
    int row0 = bid * 64 + w * 16;
    int rA0 = row0 + m_l;
    int rc0 = rA0 < NN ? rA0 : NN - 1;
    const float* pa0 = X + (size_t)rc0 * INF_ + q * 8;
    const short8* Bp = (const short8*)W1f;

    float4 xu[16];
    #pragma unroll
    for (int kc = 0; kc < 8; kc++) {
        xu[2 * kc]     = *(const float4*)(pa0 + kc * 32);
        xu[2 * kc + 1] = *(const float4*)(pa0 + kc * 32 + 4);
    }
    short8 af[8];
    #pragma unroll
    for (int kc = 0; kc < 8; kc++) {
        float4 u0 = xu[2 * kc], u1 = xu[2 * kc + 1];
        af[kc][0] = f2bf(u0.x); af[kc][1] = f2bf(u0.y); af[kc][2] = f2bf(u0.z); af[kc][3] = f2bf(u0.w);
        af[kc][4] = f2bf(u1.x); af[kc][5] = f2bf(u1.y); af[kc][6] = f2bf(u1.z); af[kc][7] = f2bf(u1.w);
    }

    float4v acc[8] = {};
    #pragma unroll
    for (int kc = 0; kc < 8; kc++) {
        #pragma unroll
        for (int n = 0; n < 8; n++) {
            short8 b = Bp[(kc * 8 + n) * 64 + l];
            acc[n] = __builtin_amdgcn_mfma_f32_16x16x32_bf16(af[kc], b, acc[n], 0, 0, 0);
        }
    }

    float vs_r[4] = {0.f, 0.f, 0.f, 0.f}, vt_r[4] = {0.f, 0.f, 0.f, 0.f};
    #pragma unroll
    for (int n = 0; n < 8; n++) {
        int col = n * 16 + m_l;
        float bias = b1[col];
        float aw0 = a1w[col], aw1 = a1w[HIDF + col];
        #pragma unroll
        for (int r = 0; r < 4; r++) {
            int row = row0 + q * 4 + r;
            float v = acc[n][r] + bias;
            v = v > 0.f ? v : expm1f(v);   // elu
            vs_r[r] += v * aw0; vt_r[r] += v * aw1;
            if (row < NN) Hb[(size_t)row * HIDF + col] = (ushort)f2bf(v);
        }
    }
    #pragma unroll
    for (int r = 0; r < 4; r++) {
        #pragma unroll
        for (int o = 1; o < 16; o <<= 1) {
            vs_r[r] += __shfl_xor(vs_r[r], o);
            vt_r[r] += __shfl_xor(vt_r[r], o);
        }
    }
    if (m_l == 0) {
        #pragma unroll
        for (int r = 0; r < 4; r++) {
            int row = row0 + q * 4 + r;
            if (row < NN) { s1s[row] = vs_r[r]; s1t[row] = vt_r[r]; }
        }
    }
}

// ---------------- part2: fine sort within bucket ----------------
__global__ __launch_bounds__(256) void k_part2(const int* __restrict__ bcur, const uint2* __restrict__ pairs,
                                               int* __restrict__ fsrc, int* __restrict__ nbeg,
                                               int* __restrict__ ncnt) {
    __shared__ int hist[256], cur[256];
    __shared__ int ws[4];
    int tid = threadIdx.x;
    int b = blockIdx.x;
    int cnt = __builtin_amdgcn_readfirstlane(bcur[b]);
    hist[tid] = 0;
    __syncthreads();

    const uint2* pb = pairs + (size_t)b * CAP;
    for (int j = tid; j < cnt; j += 256) {
        uint2 e = pb[j];
        atomicAdd(&hist[e.x & 255], 1);
    }
    __syncthreads();

    int v = hist[tid];
    int excl = excl_scan256(v, ws);
    int node = (b << 8) + tid;
    if (node < NN) { nbeg[node] = b * CAP + excl; ncnt[node] = v; }
    cur[tid] = excl;
    __syncthreads();

    for (int j = tid; j < cnt; j += 256) {
        uint2 e = pb[j];
        int pos = atomicAdd(&cur[e.x & 255], 1);
        fsrc[(size_t)b * CAP + pos] = (int)e.y;
    }
}

// ---------------- linear2 + s2 epilogue (bf16 MFMA) ----------------
__global__ __launch_bounds__(256, 3) void k_linear2(const short* __restrict__ Hin, const short* __restrict__ W2f,
                                                    const float* __restrict__ b2, ushort* __restrict__ Ob,
                                                    const float* __restrict__ a2w, float* __restrict__ s2s,
                                                    float* __restrict__ s2t) {
    int w = threadIdx.x >> 6;
    int l = threadIdx.x & 63;
    int m_l = l & 15, q = l >> 4;
    int row0 = blockIdx.x * 64 + w * 16;
    int rA0 = row0 + m_l;
    int rc0 = rA0 < NN ? rA0 : NN - 1;
    const short* pa0 = Hin + (size_t)rc0 * HIDF + q * 8;
    const short8* Bp = (const short8*)W2f;

    short8 af[4];
    #pragma unroll
    for (int kc = 0; kc < 4; kc++) af[kc] = *(const short8*)(pa0 + kc * 32);

    float4v acc[4] = {};
    #pragma unroll
    for (int kc = 0; kc < 4; kc++) {
        #pragma unroll
        for (int n = 0; n < 4; n++) {
            short8 b = Bp[(kc * 4 + n) * 64 + l];
            acc[n] = __builtin_amdgcn_mfma_f32_16x16x32_bf16(af[kc], b, acc[n], 0, 0, 0);
        }
    }

    float vs_r[4] = {0.f, 0.f, 0.f, 0.f}, vt_r[4] = {0.f, 0.f, 0.f, 0.f};
    #pragma unroll
    for (int n = 0; n < 4; n++) {
        int col = n * 16 + m_l;
        float bias = b2[col];
        float aw0 = a2w[col], aw1 = a2w[OUTF + col];
        #pragma unroll
        for (int r = 0; r < 4; r++) {
            int row = row0 + q * 4 + r;
            float v = acc[n][r] + bias;
            vs_r[r] += v * aw0; vt_r[r] += v * aw1;
            if (row < NN) Ob[(size_t)row * OUTF + col] = (ushort)f2bf(v);
        }
    }
    #pragma unroll
    for (int r = 0; r < 4; r++) {
        #pragma unroll
        for (int o = 1; o < 16; o <<= 1) {
            vs_r[r] += __shfl_xor(vs_r[r], o);
            vt_r[r] += __shfl_xor(vt_r[r], o);
        }
    }
    if (m_l == 0) {
        #pragma unroll
        for (int r = 0; r < 4; r++) {
            int row = row0 + q * 4 + r;
            if (row < NN) { s2s[row] = vs_r[r]; s2t[row] = vt_r[r]; }
        }
    }
}

// ---------------- fused softmax + gather aggregation, one wave per node ----------------

__global__ __launch_bounds__(256) void k_agg1f(const uint* __restrict__ Hb4, const int* __restrict__ nbeg,
                                               const int* __restrict__ ncnt, const int* __restrict__ fsrc,
                                               const float* __restrict__ ss, const float* __restrict__ st_,
                                               const float* __restrict__ ab, uint* __restrict__ Hagg4) {
    int wid  = (blockIdx.x * 256 + threadIdx.x) >> 6;
    int lane = threadIdx.x & 63;
    if (wid >= NN) return;
    int beg = __builtin_amdgcn_readfirstlane(nbeg[wid]);
    int deg = __builtin_amdgcn_readfirstlane(ncnt[wid]);
    int end = beg + deg;
    float bias = ab[0] + st_[wid];
    float ax = 0.f, ay = 0.f, bx = 0.f, by = 0.f;

    if (deg > 0 && deg <= 64) {
        int my_s = 0; float a = -INFINITY;
        if (lane < deg) {
            my_s = fsrc[beg + lane];
            float t = ss[my_s] + bias;
            a = t >= 0.f ? t : 0.2f * t;
        }
        float m = a;
        #pragma unroll
        for (int o = 32; o > 0; o >>= 1) m = fmaxf(m, __shfl_xor(m, o));
        float e = (lane < deg) ? __expf(a - m) : 0.f;
        float sum = e;
        #pragma unroll
        for (int o = 32; o > 0; o >>= 1) sum += __shfl_xor(sum, o);
        float p = e * (1.f / (sum + 1e-16f));
        for (int j = 0; j < deg; j += 8) {
            int sA[8]; float wA[8]; uint xA[8];
            #pragma unroll
            for (int u = 0; u < 8; u++) { sA[u] = __shfl(my_s, j + u); wA[u] = __shfl(p, j + u); }
            #pragma unroll
            for (int u = 0; u < 8; u++) xA[u] = Hb4[(size_t)sA[u] * 64 + lane];
            #pragma unroll
            for (int u = 0; u < 8; u += 2) {
                ax += wA[u] * bflo(xA[u]);         ay += wA[u] * bfhi(xA[u]);
                bx += wA[u + 1] * bflo(xA[u + 1]); by += wA[u + 1] * bfhi(xA[u + 1]);
            }
        }
    } else if (deg > 64) {
        float m = -INFINITY;
        for (int i = beg + lane; i < end; i += 64) {
            float t = ss[fsrc[i]] + bias;
            t = t >= 0.f ? t : 0.2f * t;
            m = fmaxf(m, t);
        }
        #pragma unroll
        for (int o = 32; o > 0; o >>= 1) m = fmaxf(m, __shfl_xor(m, o));
        float sum = 0.f;
        for (int i = beg + lane; i < end; i += 64) {
            float t = ss[fsrc[i]] + bias;
            t = t >= 0.f ? t : 0.2f * t;
            sum += __expf(t - m);
        }
        #pragma unroll
        for (int o = 32; o > 0; o >>= 1) sum += __shfl_xor(sum, o);
        float inv = 1.f / (sum + 1e-16f);
        for (int c = beg; c < end; c += 64) {
            int cnt = min(64, end - c);
            int my_s = 0; float p = 0.f;
            if (lane < cnt) {
                my_s = fsrc[c + lane];
                float t = ss[my_s] + bias;
                t = t >= 0.f ? t : 0.2f * t;
                p = __expf(t - m) * inv;
            }
            for (int j = 0; j < cnt; j += 4) {
                int s0 = __shfl(my_s, j),     s1 = __shfl(my_s, j + 1);
                int s2 = __shfl(my_s, j + 2), s3 = __shfl(my_s, j + 3);
                float w0 = __shfl(p, j),     w1 = __shfl(p, j + 1);
                float w2 = __shfl(p, j + 2), w3 = __shfl(p, j + 3);
                uint x0 = Hb4[(size_t)s0 * 64 + lane];
                uint x1 = Hb4[(size_t)s1 * 64 + lane];
                uint x2 = Hb4[(size_t)s2 * 64 + lane];
                uint x3 = Hb4[(size_t)s3 * 64 + lane];
                ax += w0 * bflo(x0); ay += w0 * bfhi(x0);
                bx += w1 * bflo(x1); by += w1 * bfhi(x1);
                ax += w2 * bflo(x2); ay += w2 * bfhi(x2);
                bx += w3 * bflo(x3); by += w3 * bfhi(x3);
            }
        }
    }
    float fx = ax + bx, fy = ay + by;
    uint outv = (uint)(ushort)f2bf(fx) | ((uint)(ushort)f2bf(fy) << 16);
    Hagg4[(size_t)wid * 64 + lane] = outv;
}

__global__ __launch_bounds__(256) void k_agg2f(const uint* __restrict__ Ob4, const int* __restrict__ nbeg,
                                               const int* __restrict__ ncnt, const int* __restrict__ fsrc,
                                               const float* __restrict__ ss, const float* __restrict__ st_,
                                               const float* __restrict__ ab, float* __restrict__ out) {
    int wid  = (blockIdx.x * 256 + threadIdx.x) >> 6;
    int lane = threadIdx.x & 63;
    if (wid >= NN) return;
    int half = lane >> 5, li = lane & 31;
    int beg = __builtin_amdgcn_readfirstlane(nbeg[wid]);
    int deg = __builtin_amdgcn_readfirstlane(ncnt[wid]);
    int end = beg + deg;
    float bias = ab[0] + st_[wid];
    float a0 = 0.f, a1 = 0.f;

    if (deg > 0 && deg <= 64) {
        int my_s = 0; float a = -INFINITY;
        if (lane < deg) {
            my_s = fsrc[beg + lane];
            float t = ss[my_s] + bias;
            a = t >= 0.f ? t : 0.2f * t;
        }
        float m = a;
        #pragma unroll
        for (int o = 32; o > 0; o >>= 1) m = fmaxf(m, __shfl_xor(m, o));
        float e = (lane < deg) ? __expf(a - m) : 0.f;
        float sum = e;
        #pragma unroll
        for (int o = 32; o > 0; o >>= 1) sum += __shfl_xor(sum, o);
        float p = e * (1.f / (sum + 1e-16f));
        for (int j = 0; j < deg; j += 8) {
            int e0 = j + half, e1 = j + 2 + half, e2 = j + 4 + half, e3 = j + 6 + half;
            int s0 = __shfl(my_s, e0), s1 = __shfl(my_s, e1);
            int s2 = __shfl(my_s, e2), s3 = __shfl(my_s, e3);
            float w0 = __shfl(p, e0), w1 = __shfl(p, e1);
            float w2 = __shfl(p, e2), w3 = __shfl(p, e3);
            uint x0 = Ob4[(size_t)s0 * 32 + li];
            uint x1 = Ob4[(size_t)s1 * 32 + li];
            uint x2 = Ob4[(size_t)s2 * 32 + li];
            uint x3 = Ob4[(size_t)s3 * 32 + li];
            a0 += w0 * bflo(x0); a1 += w0 * bfhi(x0);
            a0 += w1 * bflo(x1); a1 += w1 * bfhi(x1);
            a0 += w2 * bflo(x2); a1 += w2 * bfhi(x2);
            a0 += w3 * bflo(x3); a1 += w3 * bfhi(x3);
        }
    } else if (deg > 64) {
        float m = -INFINITY;
        for (int i = beg + lane; i < end; i += 64) {
            float t = ss[fsrc[i]] + bias;
            t = t >= 0.f ? t : 0.2f * t;
            m = fmaxf(m, t);
        }
        #pragma unroll
        for (int o = 32; o > 0; o >>= 1) m = fmaxf(m, __shfl_xor(m, o));
        float sum = 0.f;
        for (int i = beg + lane; i < end; i += 64) {
            float t = ss[fsrc[i]] + bias;
            t = t >= 0.f ? t : 0.2f * t;
            sum += __expf(t - m);
        }
        #pragma unroll
        for (int o = 32; o > 0; o >>= 1) sum += __shfl_xor(sum, o);
        float inv = 1.f / (sum + 1e-16f);
        for (int c = beg; c < end; c += 64) {
            int cnt = min(64, end - c);
            int my_s = 0; float p = 0.f;
            if (lane < cnt) {
                my_s = fsrc[c + lane];
                float t = ss[my_s] + bias;
                t = t >= 0.f ? t : 0.2f * t;
                p = __expf(t - m) * inv;
            }
            for (int j = 0; j < cnt; j += 4) {
                int e0 = j + half, e1 = j + 2 + half;
                int s0 = __shfl(my_s, e0), s1 = __shfl(my_s, e1);
                float w0 = __shfl(p, e0), w1 = __shfl(p, e1);
                uint x0 = Ob4[(size_t)s0 * 32 + li];
                uint x1 = Ob4[(size_t)s1 * 32 + li];
                a0 += w0 * bflo(x0); a1 += w0 * bfhi(x0);
                a0 += w1 * bflo(x1); a1 += w1 * bfhi(x1);
            }
        }
    }
    a0 += __shfl_xor(a0, 32);
    a1 += __shfl_xor(a1, 32);
    float mx = fmaxf(a0, a1);
    #pragma unroll
    for (int o = 16; o > 0; o >>= 1) mx = fmaxf(mx, __shfl_xor(mx, o));
    float es = __expf(a0 - mx) + __expf(a1 - mx);
    #pragma unroll
    for (int o = 16; o > 0; o >>= 1) es += __shfl_xor(es, o);
    float lg = __logf(es);
    if (half == 0) {
        float2 r; r.x = a0 - mx - lg; r.y = a1 - mx - lg;
        ((float2*)out)[(size_t)wid * 32 + li] = r;
    }
}

// ---------------- launcher ----------------

extern "C" void kernel_launch(void* const* d_in, const int* in_sizes, int n_in,
                              void* d_out, int out_size, void* d_ws, size_t ws_size,
                              hipStream_t stream) {
    const float* X   = (const float*)d_in[0];
    const int*   ei  = (const int*)d_in[1];
    const float* W1  = (const float*)d_in[2];
    const float* b1  = (const float*)d_in[3];
    const float* a1w = (const float*)d_in[4];
    const float* a1b = (const float*)d_in[5];
    const float* W2  = (const float*)d_in[6];
    const float* b2  = (const float*)d_in[7];
    const float* a2w = (const float*)d_in[8];
    const float* a2b = (const float*)d_in[9];
    const int* src = ei;           // edge_index[0]
    const int* tgt = ei + NE;      // edge_index[1]

    char* p = (char*)d_ws;
    size_t off = 0;
    auto alloc = [&](size_t bytes) -> char* {
        char* r = p + off;
        off = (off + bytes + 255) & ~(size_t)255;
        return r;
    };
    ushort* Hb    = (ushort*)alloc((size_t)NN * HIDF * 2);
    ushort* Hagg  = (ushort*)alloc((size_t)NN * HIDF * 2);
    ushort* Ob    = (ushort*)alloc((size_t)NN * OUTF * 2);
    short* W1f    = (short*)alloc((size_t)INF_ * HIDF * 2);
    short* W2f    = (short*)alloc((size_t)HIDF * OUTF * 2);
    float* s1s    = (float*)alloc((size_t)NN * 4);
    float* s1t    = (float*)alloc((size_t)NN * 4);
    float* s2s    = (float*)alloc((size_t)NN * 4);
    float* s2t    = (float*)alloc((size_t)NN * 4);
    int*   bcur   = (int*)alloc((size_t)NBUCK * 4);
    uint2* pairs  = (uint2*)alloc((size_t)NBUCK * CAP * 8);
    int*   fsrc   = (int*)alloc((size_t)NBUCK * CAP * 4);
    int*   nbeg   = (int*)alloc((size_t)NN * 4);
    int*   ncnt   = (int*)alloc((size_t)NN * 4);

    k_prep   <<<NPREP + 1, 256, 0, stream>>>(W1, W2, W1f, W2f, bcur);
    k_f1     <<<NPART1 + NLIN1, 256, 0, stream>>>(src, tgt, bcur, pairs,
                                                  X, W1f, b1, Hb, a1w, s1s, s1t);
    k_part2  <<<NBUCK, 256, 0, stream>>>(bcur, pairs, fsrc, nbeg, ncnt);
    k_agg1f  <<<NN / 4, 256, 0, stream>>>((const uint*)Hb, nbeg, ncnt, fsrc, s1s, s1t, a1b, (uint*)Hagg);
    k_linear2<<<NLIN1, 256, 0, stream>>>((const short*)Hagg, W2f, b2, Ob, a2w, s2s, s2t);
    k_agg2f  <<<NN / 4, 256, 0, stream>>>((const uint*)Ob, nbeg, ncnt, fsrc, s2s, s2t, a2b, (float*)d_out);
}